// Round 1
// baseline (241.503 us; speedup 1.0000x reference)
//
#include <hip/hip_runtime.h>

// GaussianRecuModel: B=512 batches, T=8192-step affine recurrence on 2-state x.
//   x_{t+1} = Mt x_t + bt,  Mt = I + dt*A - dt*(xic_t C),  bt = xic_t dy_t
//   out_t   = dt * C x_t   (state BEFORE update)
// Chunked parallel scan: compose per-chunk affine maps, serial scan over
// chunks per batch, then replay chunks to emit outputs.

#define B_  512
#define T_  8192
#define L_  32                 // steps per chunk
#define NC_ (T_ / L_)          // 256 chunks per batch
static_assert(NC_ == 256, "thread mapping assumes NC_=256");

__device__ __forceinline__ void load_consts(const float* __restrict__ Aptr,
                                            const float* __restrict__ Cptr,
                                            float& i00, float& i01, float& i10, float& i11,
                                            float& cd00, float& cd01, float& cd10, float& cd11)
{
    const float DT = 1e-3f;
    float a00 = Aptr[0], a01 = Aptr[1], a10 = Aptr[2], a11 = Aptr[3];
    float c00 = Cptr[0], c01 = Cptr[1], c10 = Cptr[2], c11 = Cptr[3];
    cd00 = c00 * DT; cd01 = c01 * DT; cd10 = c10 * DT; cd11 = c11 * DT;
    i00 = 1.0f + a00 * DT; i01 = a01 * DT;
    i10 = a10 * DT;        i11 = 1.0f + a11 * DT;
}

// Phase 1: each thread composes the affine map of one 32-step chunk.
__global__ __launch_bounds__(256) void grm_compose(
    const float* __restrict__ xic, const float* __restrict__ dy,
    const float* __restrict__ Aptr, const float* __restrict__ Cptr,
    float4* __restrict__ Mout, float2* __restrict__ vout)
{
    int g = blockIdx.x * 256 + threadIdx.x;
    int b = g >> 8;            // g / NC_
    int c = g & (NC_ - 1);

    float i00,i01,i10,i11, cd00,cd01,cd10,cd11;
    load_consts(Aptr, Cptr, i00,i01,i10,i11, cd00,cd01,cd10,cd11);

    const float4* xv = (const float4*)xic + ((size_t)b * T_ + (size_t)c * L_);
    const float2* dv = (const float2*)dy  + ((size_t)b * T_ + (size_t)c * L_);

    float M00 = 1.f, M01 = 0.f, M10 = 0.f, M11 = 1.f;
    float v0 = 0.f, v1 = 0.f;

    #pragma unroll 4
    for (int i = 0; i < L_; ++i) {
        float4 x4 = xv[i];     // xic row-major: (00,01,10,11)
        float2 d2 = dv[i];
        // Mt = (I + dt*A) - xic * (dt*C)
        float m00 = i00 - (x4.x * cd00 + x4.y * cd10);
        float m01 = i01 - (x4.x * cd01 + x4.y * cd11);
        float m10 = i10 - (x4.z * cd00 + x4.w * cd10);
        float m11 = i11 - (x4.z * cd01 + x4.w * cd11);
        float b0 = x4.x * d2.x + x4.y * d2.y;
        float b1 = x4.z * d2.x + x4.w * d2.y;
        // compose: M <- Mt*M ; v <- Mt*v + bt
        float n00 = m00 * M00 + m01 * M10;
        float n01 = m00 * M01 + m01 * M11;
        float n10 = m10 * M00 + m11 * M10;
        float n11 = m10 * M01 + m11 * M11;
        float nv0 = m00 * v0 + m01 * v1 + b0;
        float nv1 = m10 * v0 + m11 * v1 + b1;
        M00 = n00; M01 = n01; M10 = n10; M11 = n11;
        v0 = nv0; v1 = nv1;
    }
    Mout[(size_t)c * B_ + b] = make_float4(M00, M01, M10, M11);
    vout[(size_t)c * B_ + b] = make_float2(v0, v1);
}

// Phase 2: serial scan over chunk maps per batch -> chunk-start states.
__global__ __launch_bounds__(256) void grm_scan(
    const float4* __restrict__ Mc, const float2* __restrict__ vc,
    float2* __restrict__ xs)
{
    int b = blockIdx.x * 256 + threadIdx.x;   // 2 blocks of 256 = 512
    float x0 = 1.0f, x1 = 0.0f;               // initial state [1,0]
    for (int c = 0; c < NC_; ++c) {
        xs[(size_t)c * B_ + b] = make_float2(x0, x1);
        float4 M = Mc[(size_t)c * B_ + b];
        float2 v = vc[(size_t)c * B_ + b];
        float nx0 = M.x * x0 + M.y * x1 + v.x;
        float nx1 = M.z * x0 + M.w * x1 + v.y;
        x0 = nx0; x1 = nx1;
    }
}

// Phase 3: replay each chunk from its start state, emit out = dt*C*x_prev.
__global__ __launch_bounds__(256) void grm_emit(
    const float* __restrict__ xic, const float* __restrict__ dy,
    const float* __restrict__ Aptr, const float* __restrict__ Cptr,
    const float2* __restrict__ xs, float2* __restrict__ out)
{
    int g = blockIdx.x * 256 + threadIdx.x;
    int b = g >> 8;
    int c = g & (NC_ - 1);

    float i00,i01,i10,i11, cd00,cd01,cd10,cd11;
    load_consts(Aptr, Cptr, i00,i01,i10,i11, cd00,cd01,cd10,cd11);

    float2 x = xs[(size_t)c * B_ + b];
    float x0 = x.x, x1 = x.y;

    const float4* xv = (const float4*)xic + ((size_t)b * T_ + (size_t)c * L_);
    const float2* dv = (const float2*)dy  + ((size_t)b * T_ + (size_t)c * L_);
    float2* ov = out + ((size_t)b * T_ + (size_t)c * L_);

    #pragma unroll 4
    for (int i = 0; i < L_; ++i) {
        float4 x4 = xv[i];
        float2 d2 = dv[i];
        // emit BEFORE update: out = (dt*C) @ x
        ov[i] = make_float2(cd00 * x0 + cd01 * x1,
                            cd10 * x0 + cd11 * x1);
        float m00 = i00 - (x4.x * cd00 + x4.y * cd10);
        float m01 = i01 - (x4.x * cd01 + x4.y * cd11);
        float m10 = i10 - (x4.z * cd00 + x4.w * cd10);
        float m11 = i11 - (x4.z * cd01 + x4.w * cd11);
        float b0 = x4.x * d2.x + x4.y * d2.y;
        float b1 = x4.z * d2.x + x4.w * d2.y;
        float nx0 = m00 * x0 + m01 * x1 + b0;
        float nx1 = m10 * x0 + m11 * x1 + b1;
        x0 = nx0; x1 = nx1;
    }
}

extern "C" void kernel_launch(void* const* d_in, const int* in_sizes, int n_in,
                              void* d_out, int out_size, void* d_ws, size_t ws_size,
                              hipStream_t stream) {
    const float* xic  = (const float*)d_in[0];   // [B,T,2,2]
    const float* dy   = (const float*)d_in[1];   // [B,T,2]
    const float* Aptr = (const float*)d_in[2];   // [2,2]
    const float* Cptr = (const float*)d_in[3];   // [2,2]
    float* out = (float*)d_out;                  // [B,T,2]

    // workspace layout (4 MiB total):
    //   [0, 2MiB)      Mchunk  float4 [NC][B]
    //   [2MiB, 3MiB)   vchunk  float2 [NC][B]
    //   [3MiB, 4MiB)   xstart  float2 [NC][B]
    char* ws = (char*)d_ws;
    float4* Mc = (float4*)ws;
    float2* vc = (float2*)(ws + (size_t)NC_ * B_ * sizeof(float4));
    float2* xs = (float2*)(ws + (size_t)NC_ * B_ * (sizeof(float4) + sizeof(float2)));

    const int nthreads = B_ * NC_;               // 131072
    grm_compose<<<nthreads / 256, 256, 0, stream>>>(xic, dy, Aptr, Cptr, Mc, vc);
    grm_scan<<<B_ / 256, 256, 0, stream>>>(Mc, vc, xs);
    grm_emit<<<nthreads / 256, 256, 0, stream>>>(xic, dy, Aptr, Cptr, xs, (float2*)out);
}

// Round 2
// 176.919 us; speedup vs baseline: 1.3650x; 1.3650x over previous
//
#include <hip/hip_runtime.h>

// GaussianRecuModel: B=512 batches, T=8192-step affine recurrence on 2-state x.
//   x_{t+1} = Mt x_t + bt,  Mt = I + dt*A - dt*(xic_t C),  bt = xic_t dy_t
//   out_t   = dt * C x_t   (state BEFORE update)
// Chunked parallel scan: compose per-chunk affine maps (grouped cacheline-
// friendly loads), wave-parallel Kogge-Stone scan over chunk maps, replay.

#define B_  512
#define T_  8192
#define L_  32                 // steps per chunk
#define NC_ (T_ / L_)          // 256 chunks per batch
static_assert(NC_ == 256, "thread mapping assumes NC_=256");

__device__ __forceinline__ void load_consts(const float* __restrict__ Aptr,
                                            const float* __restrict__ Cptr,
                                            float& i00, float& i01, float& i10, float& i11,
                                            float& cd00, float& cd01, float& cd10, float& cd11)
{
    const float DT = 1e-3f;
    float a00 = Aptr[0], a01 = Aptr[1], a10 = Aptr[2], a11 = Aptr[3];
    float c00 = Cptr[0], c01 = Cptr[1], c10 = Cptr[2], c11 = Cptr[3];
    cd00 = c00 * DT; cd01 = c01 * DT; cd10 = c10 * DT; cd11 = c11 * DT;
    i00 = 1.0f + a00 * DT; i01 = a01 * DT;
    i10 = a10 * DT;        i11 = 1.0f + a11 * DT;
}

// Phase 1: each thread composes the affine map of one 32-step chunk.
// Loads grouped in 4-step super-steps so all touches of a 64B line are
// back-to-back (L1 hit) instead of spread over the whole loop (L1 thrash).
__global__ __launch_bounds__(256) void grm_compose(
    const float* __restrict__ xic, const float* __restrict__ dy,
    const float* __restrict__ Aptr, const float* __restrict__ Cptr,
    float4* __restrict__ Mout, float2* __restrict__ vout)
{
    int g = blockIdx.x * 256 + threadIdx.x;
    int b = g >> 8;            // g / NC_
    int c = g & (NC_ - 1);

    float i00,i01,i10,i11, cd00,cd01,cd10,cd11;
    load_consts(Aptr, Cptr, i00,i01,i10,i11, cd00,cd01,cd10,cd11);

    const float4* xv  = (const float4*)xic + ((size_t)b * T_ + (size_t)c * L_);
    const float4* dv4 = (const float4*)dy  + ((size_t)b * T_ + (size_t)c * L_) / 2;

    float M00 = 1.f, M01 = 0.f, M10 = 0.f, M11 = 1.f;
    float v0 = 0.f, v1 = 0.f;

#define STEP_COMPOSE(x4, dyx, dyy)                                     \
    {                                                                  \
        float m00 = i00 - ((x4).x * cd00 + (x4).y * cd10);             \
        float m01 = i01 - ((x4).x * cd01 + (x4).y * cd11);             \
        float m10 = i10 - ((x4).z * cd00 + (x4).w * cd10);             \
        float m11 = i11 - ((x4).z * cd01 + (x4).w * cd11);             \
        float b0 = (x4).x * (dyx) + (x4).y * (dyy);                    \
        float b1 = (x4).z * (dyx) + (x4).w * (dyy);                    \
        float n00 = m00 * M00 + m01 * M10;                             \
        float n01 = m00 * M01 + m01 * M11;                             \
        float n10 = m10 * M00 + m11 * M10;                             \
        float n11 = m10 * M01 + m11 * M11;                             \
        float nv0 = m00 * v0 + m01 * v1 + b0;                          \
        float nv1 = m10 * v0 + m11 * v1 + b1;                          \
        M00 = n00; M01 = n01; M10 = n10; M11 = n11;                    \
        v0 = nv0; v1 = nv1;                                            \
    }

    #pragma unroll 4
    for (int s = 0; s < L_ / 4; ++s) {
        float4 a0 = xv[4*s+0], a1 = xv[4*s+1], a2 = xv[4*s+2], a3 = xv[4*s+3];
        float4 d01 = dv4[2*s+0], d23 = dv4[2*s+1];
        STEP_COMPOSE(a0, d01.x, d01.y);
        STEP_COMPOSE(a1, d01.z, d01.w);
        STEP_COMPOSE(a2, d23.x, d23.y);
        STEP_COMPOSE(a3, d23.z, d23.w);
    }
#undef STEP_COMPOSE

    // ws layout [b][c]: phase-2 per-batch reads contiguous; writes coalesced
    // (c == threadIdx fastest).
    Mout[(size_t)b * NC_ + c] = make_float4(M00, M01, M10, M11);
    vout[(size_t)b * NC_ + c] = make_float2(v0, v1);
}

// Phase 2: wave-parallel scan. One 64-lane wave per batch; lane owns 4
// contiguous chunk maps, composes them locally, Kogge-Stone inclusive scan
// across lanes (affine-map composition), then emits chunk-start states.
__global__ __launch_bounds__(256) void grm_scan(
    const float4* __restrict__ Mc, const float2* __restrict__ vc,
    float2* __restrict__ xs)
{
    int wave = threadIdx.x >> 6;
    int lane = threadIdx.x & 63;
    int b = blockIdx.x * 4 + wave;

    const float4* Mb = Mc + (size_t)b * NC_;
    const float2* vb = vc + (size_t)b * NC_;
    int c0 = lane * 4;

    float4 m[4]; float2 w[4];
    #pragma unroll
    for (int i = 0; i < 4; ++i) { m[i] = Mb[c0 + i]; w[i] = vb[c0 + i]; }

    // lane-local compose P = T3 o T2 o T1 o T0
    float P00 = m[0].x, P01 = m[0].y, P10 = m[0].z, P11 = m[0].w;
    float Pv0 = w[0].x, Pv1 = w[0].y;
    #pragma unroll
    for (int i = 1; i < 4; ++i) {
        float a00 = m[i].x, a01 = m[i].y, a10 = m[i].z, a11 = m[i].w;
        float n00 = a00*P00 + a01*P10, n01 = a00*P01 + a01*P11;
        float n10 = a10*P00 + a11*P10, n11 = a10*P01 + a11*P11;
        float nv0 = a00*Pv0 + a01*Pv1 + w[i].x;
        float nv1 = a10*Pv0 + a11*Pv1 + w[i].y;
        P00 = n00; P01 = n01; P10 = n10; P11 = n11; Pv0 = nv0; Pv1 = nv1;
    }

    // inclusive Kogge-Stone over 64 lanes: S_l = P_l o ... o P_0
    float S00 = P00, S01 = P01, S10 = P10, S11 = P11, Sv0 = Pv0, Sv1 = Pv1;
    #pragma unroll
    for (int d = 1; d < 64; d <<= 1) {
        float q00 = __shfl_up(S00, d), q01 = __shfl_up(S01, d);
        float q10 = __shfl_up(S10, d), q11 = __shfl_up(S11, d);
        float qv0 = __shfl_up(Sv0, d), qv1 = __shfl_up(Sv1, d);
        if (lane >= d) {
            float n00 = S00*q00 + S01*q10, n01 = S00*q01 + S01*q11;
            float n10 = S10*q00 + S11*q10, n11 = S10*q01 + S11*q11;
            float nv0 = S00*qv0 + S01*qv1 + Sv0;
            float nv1 = S10*qv0 + S11*qv1 + Sv1;
            S00 = n00; S01 = n01; S10 = n10; S11 = n11; Sv0 = nv0; Sv1 = nv1;
        }
    }

    // exclusive = shift by one; lane 0 = identity
    float E00 = __shfl_up(S00, 1), E01 = __shfl_up(S01, 1);
    float E10 = __shfl_up(S10, 1), E11 = __shfl_up(S11, 1);
    float Ev0 = __shfl_up(Sv0, 1), Ev1 = __shfl_up(Sv1, 1);
    if (lane == 0) { E00 = 1.f; E01 = 0.f; E10 = 0.f; E11 = 1.f; Ev0 = 0.f; Ev1 = 0.f; }
    (void)E01; (void)E11;

    // x at start of chunk c0, from x_init = [1,0]: E.col0 + Ev
    float x0 = E00 + Ev0, x1 = E10 + Ev1;

    float2* xb = xs + (size_t)b * NC_;
    #pragma unroll
    for (int i = 0; i < 4; ++i) {
        xb[c0 + i] = make_float2(x0, x1);
        float nx0 = m[i].x * x0 + m[i].y * x1 + w[i].x;
        float nx1 = m[i].z * x0 + m[i].w * x1 + w[i].y;
        x0 = nx0; x1 = nx1;
    }
}

// Phase 3: replay each chunk from its start state, emit out = dt*C*x_prev.
// Same grouped-load structure; outputs buffered 4 steps and stored as 2x
// float4 (32B contiguous per lane per super-step).
__global__ __launch_bounds__(256) void grm_emit(
    const float* __restrict__ xic, const float* __restrict__ dy,
    const float* __restrict__ Aptr, const float* __restrict__ Cptr,
    const float2* __restrict__ xs, float4* __restrict__ out4)
{
    int g = blockIdx.x * 256 + threadIdx.x;
    int b = g >> 8;
    int c = g & (NC_ - 1);

    float i00,i01,i10,i11, cd00,cd01,cd10,cd11;
    load_consts(Aptr, Cptr, i00,i01,i10,i11, cd00,cd01,cd10,cd11);

    float2 x = xs[(size_t)b * NC_ + c];
    float x0 = x.x, x1 = x.y;

    const float4* xv  = (const float4*)xic + ((size_t)b * T_ + (size_t)c * L_);
    const float4* dv4 = (const float4*)dy  + ((size_t)b * T_ + (size_t)c * L_) / 2;
    float4* ov4 = out4 + ((size_t)b * T_ + (size_t)c * L_) / 2;

#define STEP_EMIT(x4, dyx, dyy, ox, oy)                                \
    {                                                                  \
        (ox) = cd00 * x0 + cd01 * x1;                                  \
        (oy) = cd10 * x0 + cd11 * x1;                                  \
        float m00 = i00 - ((x4).x * cd00 + (x4).y * cd10);             \
        float m01 = i01 - ((x4).x * cd01 + (x4).y * cd11);             \
        float m10 = i10 - ((x4).z * cd00 + (x4).w * cd10);             \
        float m11 = i11 - ((x4).z * cd01 + (x4).w * cd11);             \
        float b0 = (x4).x * (dyx) + (x4).y * (dyy);                    \
        float b1 = (x4).z * (dyx) + (x4).w * (dyy);                    \
        float nx0 = m00 * x0 + m01 * x1 + b0;                          \
        float nx1 = m10 * x0 + m11 * x1 + b1;                          \
        x0 = nx0; x1 = nx1;                                            \
    }

    #pragma unroll 4
    for (int s = 0; s < L_ / 4; ++s) {
        float4 a0 = xv[4*s+0], a1 = xv[4*s+1], a2 = xv[4*s+2], a3 = xv[4*s+3];
        float4 d01 = dv4[2*s+0], d23 = dv4[2*s+1];
        float o0x, o0y, o1x, o1y, o2x, o2y, o3x, o3y;
        STEP_EMIT(a0, d01.x, d01.y, o0x, o0y);
        STEP_EMIT(a1, d01.z, d01.w, o1x, o1y);
        STEP_EMIT(a2, d23.x, d23.y, o2x, o2y);
        STEP_EMIT(a3, d23.z, d23.w, o3x, o3y);
        ov4[2*s+0] = make_float4(o0x, o0y, o1x, o1y);
        ov4[2*s+1] = make_float4(o2x, o2y, o3x, o3y);
    }
#undef STEP_EMIT
}

extern "C" void kernel_launch(void* const* d_in, const int* in_sizes, int n_in,
                              void* d_out, int out_size, void* d_ws, size_t ws_size,
                              hipStream_t stream) {
    const float* xic  = (const float*)d_in[0];   // [B,T,2,2]
    const float* dy   = (const float*)d_in[1];   // [B,T,2]
    const float* Aptr = (const float*)d_in[2];   // [2,2]
    const float* Cptr = (const float*)d_in[3];   // [2,2]
    float* out = (float*)d_out;                  // [B,T,2]

    // workspace layout (4 MiB total), all [b][c]:
    //   [0, 2MiB)      Mchunk  float4 [B][NC]
    //   [2MiB, 3MiB)   vchunk  float2 [B][NC]
    //   [3MiB, 4MiB)   xstart  float2 [B][NC]
    char* ws = (char*)d_ws;
    float4* Mc = (float4*)ws;
    float2* vc = (float2*)(ws + (size_t)NC_ * B_ * sizeof(float4));
    float2* xs = (float2*)(ws + (size_t)NC_ * B_ * (sizeof(float4) + sizeof(float2)));

    const int nthreads = B_ * NC_;               // 131072
    grm_compose<<<nthreads / 256, 256, 0, stream>>>(xic, dy, Aptr, Cptr, Mc, vc);
    grm_scan<<<B_ / 4, 256, 0, stream>>>(Mc, vc, xs);
    grm_emit<<<nthreads / 256, 256, 0, stream>>>(xic, dy, Aptr, Cptr, xs, (float4*)out);
}

// Round 3
// 146.966 us; speedup vs baseline: 1.6433x; 1.2038x over previous
//
#include <hip/hip_runtime.h>

// GaussianRecuModel: B=512 batches, T=8192-step affine recurrence on 2-state x.
//   x_{t+1} = Mt x_t + bt,  Mt = I + dt*A - dt*(xic_t C),  bt = xic_t dy_t
//   out_t   = dt * C x_t   (state BEFORE update)
//
// Single-pass fused kernel: one 1024-thread block per batch. Each thread
// holds its 8 steps of input in REGISTERS (48 VGPRs), composes a thread-local
// affine map, block-level scan (wave Kogge-Stone + LDS wave-prefix), then
// replays from registers. Inputs read exactly once: 96 MiB in + 32 MiB out.

#define B_   512
#define T_   8192
#define LPT  8                  // steps per thread
#define NT   1024               // threads per block
static_assert(NT * LPT == T_, "one block covers one batch");

struct Aff { float m00, m01, m10, m11, v0, v1; };

// r = later o earlier  (apply earlier first): r.M = L.M * E.M ; r.v = L.M*E.v + L.v
__device__ __forceinline__ Aff aff_compose(const Aff& L, const Aff& E) {
    Aff r;
    r.m00 = L.m00*E.m00 + L.m01*E.m10;
    r.m01 = L.m00*E.m01 + L.m01*E.m11;
    r.m10 = L.m10*E.m00 + L.m11*E.m10;
    r.m11 = L.m10*E.m01 + L.m11*E.m11;
    r.v0  = L.m00*E.v0  + L.m01*E.v1 + L.v0;
    r.v1  = L.m10*E.v0  + L.m11*E.v1 + L.v1;
    return r;
}

__device__ __forceinline__ Aff aff_identity() {
    Aff r; r.m00 = 1.f; r.m01 = 0.f; r.m10 = 0.f; r.m11 = 1.f; r.v0 = 0.f; r.v1 = 0.f;
    return r;
}

__global__ __launch_bounds__(NT) void grm_fused(
    const float* __restrict__ xic, const float* __restrict__ dy,
    const float* __restrict__ Aptr, const float* __restrict__ Cptr,
    float4* __restrict__ out4)
{
    __shared__ float wtot[16][6];     // per-wave inclusive totals

    const int b    = blockIdx.x;
    const int tid  = threadIdx.x;
    const int lane = tid & 63;
    const int wave = tid >> 6;

    const float DT = 1e-3f;
    const float c00 = Cptr[0], c01 = Cptr[1], c10 = Cptr[2], c11 = Cptr[3];
    const float cd00 = c00*DT, cd01 = c01*DT, cd10 = c10*DT, cd11 = c11*DT;
    const float i00 = 1.0f + Aptr[0]*DT, i01 = Aptr[1]*DT;
    const float i10 = Aptr[2]*DT,        i11 = 1.0f + Aptr[3]*DT;

    // ---- load this thread's 8 steps into registers (grouped, full-line use)
    const float4* xv = (const float4*)xic + ((size_t)b * T_ + tid * LPT);
    const float4* dv = (const float4*)dy  + ((size_t)b * T_ + tid * LPT) / 2;

    float4 a[LPT];
    float4 d[LPT/2];
    #pragma unroll
    for (int i = 0; i < LPT; ++i)   a[i] = xv[i];
    #pragma unroll
    for (int i = 0; i < LPT/2; ++i) d[i] = dv[i];

    // per-step map from registers
#define STEP_MAP(i, S)                                                  \
    {                                                                   \
        const float4 x4 = a[i];                                         \
        const float dyx = ((i)&1) ? d[(i)>>1].z : d[(i)>>1].x;          \
        const float dyy = ((i)&1) ? d[(i)>>1].w : d[(i)>>1].y;          \
        (S).m00 = i00 - (x4.x*cd00 + x4.y*cd10);                        \
        (S).m01 = i01 - (x4.x*cd01 + x4.y*cd11);                        \
        (S).m10 = i10 - (x4.z*cd00 + x4.w*cd10);                        \
        (S).m11 = i11 - (x4.z*cd01 + x4.w*cd11);                        \
        (S).v0  = x4.x*dyx + x4.y*dyy;                                  \
        (S).v1  = x4.z*dyx + x4.w*dyy;                                  \
    }

    // ---- thread-local compose: P = T7 o ... o T0
    Aff P;
    STEP_MAP(0, P);
    #pragma unroll
    for (int i = 1; i < LPT; ++i) { Aff s; STEP_MAP(i, s); P = aff_compose(s, P); }

    // ---- wave Kogge-Stone inclusive scan (64 lanes)
    Aff S = P;
    #pragma unroll
    for (int sh = 1; sh < 64; sh <<= 1) {
        Aff q;
        q.m00 = __shfl_up(S.m00, sh); q.m01 = __shfl_up(S.m01, sh);
        q.m10 = __shfl_up(S.m10, sh); q.m11 = __shfl_up(S.m11, sh);
        q.v0  = __shfl_up(S.v0,  sh); q.v1  = __shfl_up(S.v1,  sh);
        if (lane >= sh) S = aff_compose(S, q);
    }

    // ---- wave totals -> LDS
    if (lane == 63) {
        wtot[wave][0] = S.m00; wtot[wave][1] = S.m01;
        wtot[wave][2] = S.m10; wtot[wave][3] = S.m11;
        wtot[wave][4] = S.v0;  wtot[wave][5] = S.v1;
    }
    __syncthreads();

    // ---- wave-exclusive prefix (serial over earlier waves; <=15 composes)
    Aff Ew = aff_identity();
    for (int w = 0; w < wave; ++w) {
        Aff t;
        t.m00 = wtot[w][0]; t.m01 = wtot[w][1];
        t.m10 = wtot[w][2]; t.m11 = wtot[w][3];
        t.v0  = wtot[w][4]; t.v1  = wtot[w][5];
        Ew = aff_compose(t, Ew);
    }

    // ---- lane-exclusive prefix within wave (shift inclusive by 1)
    Aff El;
    El.m00 = __shfl_up(S.m00, 1); El.m01 = __shfl_up(S.m01, 1);
    El.m10 = __shfl_up(S.m10, 1); El.m11 = __shfl_up(S.m11, 1);
    El.v0  = __shfl_up(S.v0,  1); El.v1  = __shfl_up(S.v1,  1);
    if (lane == 0) El = aff_identity();

    // total exclusive prefix for this thread; x_start = E*[1,0] + Ev
    Aff E = aff_compose(El, Ew);
    float x0 = E.m00 + E.v0;
    float x1 = E.m10 + E.v1;

    // ---- replay from registers, buffer outputs, store 4x float4 (64B/lane)
    float o[LPT][2];
    #pragma unroll
    for (int i = 0; i < LPT; ++i) {
        o[i][0] = cd00*x0 + cd01*x1;
        o[i][1] = cd10*x0 + cd11*x1;
        Aff s; STEP_MAP(i, s);
        float nx0 = s.m00*x0 + s.m01*x1 + s.v0;
        float nx1 = s.m10*x0 + s.m11*x1 + s.v1;
        x0 = nx0; x1 = nx1;
    }
#undef STEP_MAP

    float4* ov = out4 + ((size_t)b * T_ + tid * LPT) / 2;
    #pragma unroll
    for (int i = 0; i < LPT/2; ++i)
        ov[i] = make_float4(o[2*i][0], o[2*i][1], o[2*i+1][0], o[2*i+1][1]);
}

extern "C" void kernel_launch(void* const* d_in, const int* in_sizes, int n_in,
                              void* d_out, int out_size, void* d_ws, size_t ws_size,
                              hipStream_t stream) {
    const float* xic  = (const float*)d_in[0];   // [B,T,2,2]
    const float* dy   = (const float*)d_in[1];   // [B,T,2]
    const float* Aptr = (const float*)d_in[2];   // [2,2]
    const float* Cptr = (const float*)d_in[3];   // [2,2]
    float4* out = (float4*)d_out;                // [B,T,2]

    grm_fused<<<B_, NT, 0, stream>>>(xic, dy, Aptr, Cptr, out);
}

// Round 4
// 140.375 us; speedup vs baseline: 1.7204x; 1.0470x over previous
//
#include <hip/hip_runtime.h>

// GaussianRecuModel: B=512 batches, T=8192-step affine recurrence on 2-state x.
//   x_{t+1} = Mt x_t + bt,  Mt = I + dt*A - dt*(xic_t C),  bt = xic_t dy_t
//   out_t   = dt * C x_t   (state BEFORE update)
//
// Single-pass fused kernel, one 1024-thread block per batch, 8 steps/thread
// in registers. R4: ALL global accesses are wave-coalesced (lane-contiguous
// float4); a 4 KiB-per-wave XOR-swizzled LDS slice transposes between
// "coalesced" order and "8 contiguous steps per thread" order, bank-conflict
// free in both directions. (R3 was request-pipe bound: lane-stride-128B loads
// touched 64 lines/instr.)

#define B_   512
#define T_   8192
#define LPT  8                  // steps per thread
#define NT   1024               // threads per block (16 waves)
static_assert(NT * LPT == T_, "one block covers one batch");

struct Aff { float m00, m01, m10, m11, v0, v1; };

__device__ __forceinline__ Aff aff_compose(const Aff& L, const Aff& E) {
    Aff r;
    r.m00 = L.m00*E.m00 + L.m01*E.m10;
    r.m01 = L.m00*E.m01 + L.m01*E.m11;
    r.m10 = L.m10*E.m00 + L.m11*E.m10;
    r.m11 = L.m10*E.m01 + L.m11*E.m11;
    r.v0  = L.m00*E.v0  + L.m01*E.v1 + L.v0;
    r.v1  = L.m10*E.v0  + L.m11*E.v1 + L.v1;
    return r;
}

__device__ __forceinline__ Aff aff_identity() {
    Aff r; r.m00 = 1.f; r.m01 = 0.f; r.m10 = 0.f; r.m11 = 1.f; r.v0 = 0.f; r.v1 = 0.f;
    return r;
}

__global__ __launch_bounds__(NT, 4) void grm_fused(
    const float* __restrict__ xic, const float* __restrict__ dy,
    const float* __restrict__ Aptr, const float* __restrict__ Cptr,
    float4* __restrict__ out4)
{
    // 16 waves x 256 float4 (4 KiB) = 64 KiB. Each wave uses ONLY its slice
    // except for the wtot exchange (guarded by the two barriers).
    __shared__ float4 lds4[16 * 256];

    const int b    = blockIdx.x;
    const int tid  = threadIdx.x;
    const int lane = tid & 63;
    const int wave = tid >> 6;

    float4* slice = lds4 + wave * 256;

    const float DT = 1e-3f;
    const float cd00 = Cptr[0]*DT, cd01 = Cptr[1]*DT;
    const float cd10 = Cptr[2]*DT, cd11 = Cptr[3]*DT;
    const float i00 = 1.0f + Aptr[0]*DT, i01 = Aptr[1]*DT;
    const float i10 = Aptr[2]*DT,        i11 = 1.0f + Aptr[3]*DT;

    // global bases in float4 units; wave covers 512 steps
    const int wbase = b * T_ + wave * 512;                 // step index
    const float4* xw = (const float4*)xic + wbase;          // 512 float4 / wave
    const float4* dw = (const float4*)dy  + (wbase >> 1);   // 256 float4 / wave
    float4*       ow = out4 + (wbase >> 1);                 // 256 float4 / wave

    // ---- issue ALL global loads, fully coalesced (lane-contiguous) ----
    float4 t[8], u[4];
    #pragma unroll
    for (int j = 0; j < 8; ++j) t[j] = xw[j*64 + lane];
    #pragma unroll
    for (int j = 0; j < 4; ++j) u[j] = dw[j*64 + lane];

    // ---- xic transpose: two owner-rounds through the 4 KiB slice ----
    // owner o = f>>3 (f = float4 index in wave span), slot = f&7.
    // swizzled addr (float4 units): rel*8 + (slot ^ (rel&7)), rel = o - 32*rr.
    float4 a[LPT];
    #pragma unroll
    for (int rr = 0; rr < 2; ++rr) {
        #pragma unroll
        for (int jj = 0; jj < 4; ++jj) {
            int j = 4*rr + jj;
            int f = j*64 + lane;
            int rel = (f >> 3) & 31;
            slice[rel*8 + ((lane & 7) ^ (rel & 7))] = t[j];
        }
        if ((lane >> 5) == rr) {
            int rel = lane & 31;
            #pragma unroll
            for (int s = 0; s < LPT; ++s)
                a[s] = slice[rel*8 + (s ^ (rel & 7))];
        }
    }

    // ---- dy transpose: one round. owner o = f>>2, slot = f&3. ----
    #pragma unroll
    for (int j = 0; j < 4; ++j) {
        int f = j*64 + lane;
        int o = f >> 2;
        slice[o*4 + ((lane & 3) ^ (o & 3))] = u[j];
    }
    float4 d[4];
    #pragma unroll
    for (int s = 0; s < 4; ++s)
        d[s] = slice[lane*4 + (s ^ (lane & 3))];

#define STEP_MAP(i, S)                                                  \
    {                                                                   \
        const float4 x4 = a[i];                                         \
        const float dyx = ((i)&1) ? d[(i)>>1].z : d[(i)>>1].x;          \
        const float dyy = ((i)&1) ? d[(i)>>1].w : d[(i)>>1].y;          \
        (S).m00 = i00 - (x4.x*cd00 + x4.y*cd10);                        \
        (S).m01 = i01 - (x4.x*cd01 + x4.y*cd11);                        \
        (S).m10 = i10 - (x4.z*cd00 + x4.w*cd10);                        \
        (S).m11 = i11 - (x4.z*cd01 + x4.w*cd11);                        \
        (S).v0  = x4.x*dyx + x4.y*dyy;                                  \
        (S).v1  = x4.z*dyx + x4.w*dyy;                                  \
    }

    // ---- thread-local compose: P = T7 o ... o T0 ----
    Aff P;
    STEP_MAP(0, P);
    #pragma unroll
    for (int i = 1; i < LPT; ++i) { Aff s; STEP_MAP(i, s); P = aff_compose(s, P); }

    // ---- wave Kogge-Stone inclusive scan (64 lanes) ----
    Aff S = P;
    #pragma unroll
    for (int sh = 1; sh < 64; sh <<= 1) {
        Aff q;
        q.m00 = __shfl_up(S.m00, sh); q.m01 = __shfl_up(S.m01, sh);
        q.m10 = __shfl_up(S.m10, sh); q.m11 = __shfl_up(S.m11, sh);
        q.v0  = __shfl_up(S.v0,  sh); q.v1  = __shfl_up(S.v1,  sh);
        if (lane >= sh) S = aff_compose(S, q);
    }

    // ---- wave totals -> own slice header (slice free: a,d in regs) ----
    if (lane == 63) {
        float* h = (float*)slice;
        h[0] = S.m00; h[1] = S.m01; h[2] = S.m10; h[3] = S.m11;
        h[4] = S.v0;  h[5] = S.v1;
    }
    __syncthreads();

    // ---- wave-exclusive prefix (serial over earlier waves' headers) ----
    Aff Ew = aff_identity();
    for (int w = 0; w < wave; ++w) {
        const float* h = (const float*)(lds4 + w * 256);
        Aff t2;
        t2.m00 = h[0]; t2.m01 = h[1]; t2.m10 = h[2]; t2.m11 = h[3];
        t2.v0  = h[4]; t2.v1  = h[5];
        Ew = aff_compose(t2, Ew);
    }
    __syncthreads();   // headers consumed; slices reusable for out staging

    // ---- lane-exclusive prefix within wave ----
    Aff El;
    El.m00 = __shfl_up(S.m00, 1); El.m01 = __shfl_up(S.m01, 1);
    El.m10 = __shfl_up(S.m10, 1); El.m11 = __shfl_up(S.m11, 1);
    El.v0  = __shfl_up(S.v0,  1); El.v1  = __shfl_up(S.v1,  1);
    if (lane == 0) El = aff_identity();

    Aff E = aff_compose(El, Ew);
    float x0 = E.m00 + E.v0;
    float x1 = E.m10 + E.v1;

    // ---- replay from registers ----
    float4 o4[4];
    #pragma unroll
    for (int i = 0; i < LPT; ++i) {
        float oxx = cd00*x0 + cd01*x1;
        float oyy = cd10*x0 + cd11*x1;
        if (i & 1) { o4[i>>1].z = oxx; o4[i>>1].w = oyy; }
        else       { o4[i>>1].x = oxx; o4[i>>1].y = oyy; }
        Aff s; STEP_MAP(i, s);
        float nx0 = s.m00*x0 + s.m01*x1 + s.v0;
        float nx1 = s.m10*x0 + s.m11*x1 + s.v1;
        x0 = nx0; x1 = nx1;
    }
#undef STEP_MAP

    // ---- out transpose: own-order -> coalesced stores ----
    #pragma unroll
    for (int s = 0; s < 4; ++s)
        slice[lane*4 + (s ^ (lane & 3))] = o4[s];
    #pragma unroll
    for (int j = 0; j < 4; ++j) {
        int f = j*64 + lane;
        int o = f >> 2;
        ow[f] = slice[o*4 + ((lane & 3) ^ (o & 3))];
    }
}

extern "C" void kernel_launch(void* const* d_in, const int* in_sizes, int n_in,
                              void* d_out, int out_size, void* d_ws, size_t ws_size,
                              hipStream_t stream) {
    const float* xic  = (const float*)d_in[0];   // [B,T,2,2]
    const float* dy   = (const float*)d_in[1];   // [B,T,2]
    const float* Aptr = (const float*)d_in[2];   // [2,2]
    const float* Cptr = (const float*)d_in[3];   // [2,2]
    float4* out = (float4*)d_out;                // [B,T,2]

    grm_fused<<<B_, NT, 0, stream>>>(xic, dy, Aptr, Cptr, out);
}